// Round 5
// baseline (6479.318 us; speedup 1.0000x reference)
//
#include <hip/hip_runtime.h>
#include <hip/hip_bf16.h>

using bf16 = __hip_bfloat16;
typedef __attribute__((ext_vector_type(8))) short short8;
typedef __attribute__((ext_vector_type(4))) float f32x4;

static __device__ __forceinline__ float b2f(unsigned short s) {
    unsigned u = ((unsigned)s) << 16;
    return __builtin_bit_cast(float, u);
}
static __device__ __forceinline__ short f2b(float f) {
    __hip_bfloat16 h = __float2bfloat16(f);
    return __builtin_bit_cast(short, h);
}
static __device__ __forceinline__ void load_lds16(const void* g, void* l) {
    __builtin_amdgcn_global_load_lds(
        (const __attribute__((address_space(1))) void*)g,
        (__attribute__((address_space(3))) void*)l, 16, 0, 0);
}

// ---------------- f32 -> bf16 conversion (8 elems/thread) ----------------
__global__ void f32_to_bf16_vec(const float* __restrict__ in, bf16* __restrict__ out, int n8) {
    int i = blockIdx.x * blockDim.x + threadIdx.x;
    if (i >= n8) return;
    const f32x4* p = (const f32x4*)(in + (size_t)i * 8);
    f32x4 a = p[0], b = p[1];
    short8 o;
    o[0] = f2b(a[0]); o[1] = f2b(a[1]); o[2] = f2b(a[2]); o[3] = f2b(a[3]);
    o[4] = f2b(b[0]); o[5] = f2b(b[1]); o[6] = f2b(b[2]); o[7] = f2b(b[3]);
    *(short8*)(out + (size_t)i * 8) = o;
}

// ---------------- GEMM: C = act(X @ W^T + bias), bf16 in/out ----------------
template<int K, bool RELU>
__global__ __launch_bounds__(256) void gemm_xwt(
    const bf16* __restrict__ X, const bf16* __restrict__ W,
    const float* __restrict__ bias, bf16* __restrict__ C, int Nout)
{
    __shared__ bf16 As[128][40];
    __shared__ bf16 Bs[128][40];
    const int tid  = threadIdx.x;
    const int wave = tid >> 6, lane = tid & 63;
    const int wr = wave >> 1, wc = wave & 1;
    const long Mbase = (long)blockIdx.x * 128;
    const int  Nbase = blockIdx.y * 128;
    const int kg = (lane >> 4) * 8;

    f32x4 acc[4][4];
#pragma unroll
    for (int i = 0; i < 4; ++i)
#pragma unroll
        for (int j = 0; j < 4; ++j) acc[i][j] = (f32x4){0.f, 0.f, 0.f, 0.f};

    for (int kb = 0; kb < K / 32; ++kb) {
        __syncthreads();
#pragma unroll
        for (int q = 0; q < 2; ++q) {
            int idx = q * 256 + tid;
            int row = idx >> 2, kp = (idx & 3) * 8;
            *(short8*)&As[row][kp] = *(const short8*)&X[(Mbase + row) * K + kb * 32 + kp];
            *(short8*)&Bs[row][kp] = *(const short8*)&W[(long)(Nbase + row) * K + kb * 32 + kp];
        }
        __syncthreads();
        short8 a[4], b[4];
#pragma unroll
        for (int mt = 0; mt < 4; ++mt)
            a[mt] = *(const short8*)&As[wr * 64 + mt * 16 + (lane & 15)][kg];
#pragma unroll
        for (int nt = 0; nt < 4; ++nt)
            b[nt] = *(const short8*)&Bs[wc * 64 + nt * 16 + (lane & 15)][kg];
#pragma unroll
        for (int mt = 0; mt < 4; ++mt)
#pragma unroll
            for (int nt = 0; nt < 4; ++nt)
                acc[mt][nt] = __builtin_amdgcn_mfma_f32_16x16x32_bf16(a[mt], b[nt], acc[mt][nt], 0, 0, 0);
    }

#pragma unroll
    for (int mt = 0; mt < 4; ++mt) {
        int row0 = wr * 64 + mt * 16 + (lane >> 4) * 4;
#pragma unroll
        for (int nt = 0; nt < 4; ++nt) {
            int col = Nbase + wc * 64 + nt * 16 + (lane & 15);
            float bv = bias[col];
#pragma unroll
            for (int r = 0; r < 4; ++r) {
                float v = acc[mt][nt][r] + bv;
                if (RELU) v = fmaxf(v, 0.f);
                C[(Mbase + row0 + r) * (long)Nout + col] = __float2bfloat16(v);
            }
        }
    }
}

// ---------------- LayerNorm rows of 512, bf16 -> bf16 ----------------
__global__ __launch_bounds__(256) void ln_rows512(
    const bf16* __restrict__ in, bf16* __restrict__ out,
    const float* __restrict__ g, const float* __restrict__ be)
{
    const int lane = threadIdx.x & 63;
    const long row = (long)blockIdx.x * 4 + (threadIdx.x >> 6);
    const bf16* rp = in + row * 512;
    short8 v = *(const short8*)&rp[lane * 8];
    float x[8]; float s = 0.f, sq = 0.f;
#pragma unroll
    for (int j = 0; j < 8; ++j) { x[j] = b2f((unsigned short)v[j]); s += x[j]; sq += x[j] * x[j]; }
#pragma unroll
    for (int m = 1; m < 64; m <<= 1) { s += __shfl_xor(s, m); sq += __shfl_xor(sq, m); }
    float mu   = s * (1.f / 512.f);
    float var  = sq * (1.f / 512.f) - mu * mu;
    float rstd = rsqrtf(var + 1e-5f);
    short8 o;
#pragma unroll
    for (int j = 0; j < 8; ++j) {
        int c = lane * 8 + j;
        o[j] = f2b((x[j] - mu) * rstd * g[c] + be[c]);
    }
    *(short8*)(out + row * 512 + lane * 8) = o;
}

// ---------------- GRU scan v5: Whh register-resident (pinned) ----------------
// 32 blocks x 16 batch rows, 1024 threads = 16 waves (4/SIMD).
// Wave w owns h-cols [32w,32w+32) for ALL 3 gates: Whh slice (96x512 bf16)
// pinned in 256 AGPRs + 128 VGPRs via empty-asm keep-alives. h master f32 regs.
// gi slab staged 1 step ahead via global_load_lds (row stride 3088B: bank-safe).
__global__ __launch_bounds__(1024) void gru_scan5(
    const bf16* __restrict__ gi, const float* __restrict__ on_reset,
    const float* __restrict__ hx, const bf16* __restrict__ Whh,
    const float* __restrict__ bhh, const float* __restrict__ gr,
    const float* __restrict__ br, float* __restrict__ out, float* __restrict__ hT)
{
    __shared__ char  giS[16 * 3088];   // 49408 B, rows padded to 3088B (bank stride 4)
    __shared__ bf16  hb[16][520];      // bf16 h (pre-masked), row stride 1040B
    __shared__ float lnS[16][16];      // [row][wave] partial sums
    __shared__ float lnQ[16][16];

    const int tid  = threadIdx.x;
    const int w    = tid >> 6, lane = tid & 63;
    const int lc   = lane & 15, kg = lane >> 4;
    const int n0   = blockIdx.x * 16;
    const int cw0  = w * 32;

    // ---- Whh slice -> registers (B-fragments), once; PIN so it can't sink ----
    short8 wB[6][16];
#pragma unroll
    for (int ct = 0; ct < 6; ++ct) {
        const int wrow = (ct >> 1) * 512 + cw0 + (ct & 1) * 16 + lc;
        const bf16* wp = Whh + ((size_t)wrow << 9) + kg * 8;
#pragma unroll
        for (int kc = 0; kc < 16; ++kc)
            wB[ct][kc] = *(const short8*)&wp[kc * 32];
    }
#pragma unroll
    for (int ct = 0; ct < 6; ++ct)
#pragma unroll
        for (int kc = 0; kc < 16; ++kc) {
            if (ct < 4) asm volatile("" : "+a"(wB[ct][kc]));  // 4*16*4 = 256 AGPRs
            else        asm volatile("" : "+v"(wB[ct][kc]));  // 2*16*4 = 128 VGPRs
        }

    // ---- hoisted per-lane constants ----
    float bh[6], grg[2], brb[2];
#pragma unroll
    for (int j2 = 0; j2 < 2; ++j2) {
        const int col = cw0 + j2 * 16 + lc;
        bh[j2]     = bhh[col];
        bh[2 + j2] = bhh[512 + col];
        bh[4 + j2] = bhh[1024 + col];
        grg[j2] = gr[col];
        brb[j2] = br[col];
    }

    // ---- h master init + hb(0) ----
    float hreg[2][4];
#pragma unroll
    for (int r = 0; r < 4; ++r) {
        const int row = kg * 4 + r;
        const float m0 = on_reset[n0 + row];
#pragma unroll
        for (int j2 = 0; j2 < 2; ++j2) {
            const int col = cw0 + j2 * 16 + lc;
            float v = hx[(size_t)(n0 + row) * 512 + col];
            hreg[j2][r] = v;
            hb[row][col] = __float2bfloat16(v * m0);
        }
    }
    // ---- issue gi(0): wave w stages row w (3KB = 3 x 1KB chunks) ----
    {
        const char* gsrc = (const char*)gi + ((size_t)(n0 + w)) * 3072;
        char* ldst = giS + (size_t)w * 3088;
#pragma unroll
        for (int i = 0; i < 3; ++i)
            load_lds16(gsrc + i * 1024 + lane * 16, ldst + i * 1024);
    }
    __syncthreads();

#pragma unroll 1
    for (int t = 0; t < 128; ++t) {
        // [A] masks for t and t+1
        float mcur[4], mnx[4];
#pragma unroll
        for (int r = 0; r < 4; ++r) {
            const int row = kg * 4 + r;
            mcur[r] = on_reset[(size_t)t * 512 + n0 + row];
            mnx[r]  = (t < 127) ? on_reset[(size_t)(t + 1) * 512 + n0 + row] : 1.f;
        }

        // [B] MFMA phase: gh for this wave's 96 output cols (B pinned in regs)
        f32x4 acc[6];
#pragma unroll
        for (int ct = 0; ct < 6; ++ct) acc[ct] = (f32x4){0.f, 0.f, 0.f, 0.f};
#pragma unroll
        for (int kc = 0; kc < 16; ++kc) {
            short8 a = *(const short8*)&hb[lc][kc * 32 + kg * 8];
#pragma unroll
            for (int ct = 0; ct < 6; ++ct)
                acc[ct] = __builtin_amdgcn_mfma_f32_16x16x32_bf16(a, wB[ct][kc], acc[ct], 0, 0, 0);
        }

        // [C] LN-finalize(t-1) + coalesced out stores
        if (t > 0) {
#pragma unroll
            for (int r = 0; r < 4; ++r) {
                const int row = kg * 4 + r;
                float s = 0.f, q = 0.f;
#pragma unroll
                for (int q4 = 0; q4 < 4; ++q4) {
                    f32x4 vs = *(const f32x4*)&lnS[row][q4 * 4];
                    f32x4 vq = *(const f32x4*)&lnQ[row][q4 * 4];
                    s += vs[0] + vs[1] + vs[2] + vs[3];
                    q += vq[0] + vq[1] + vq[2] + vq[3];
                }
                const float mu   = s * (1.f / 512.f);
                const float var  = q * (1.f / 512.f) - mu * mu;
                const float rstd = rsqrtf(var + 1e-5f);
                float* orow = out + ((size_t)(t - 1) * 512 + n0 + row) * 512;
#pragma unroll
                for (int j2 = 0; j2 < 2; ++j2) {
                    const int col = cw0 + j2 * 16 + lc;
                    float o = (hreg[j2][r] - mu) * rstd * grg[j2] + brb[j2];
                    __builtin_nontemporal_store(o, orow + col);
                }
            }
        }

        __syncthreads();   // [D] gi(t) arrived; hb/lnS reads done

        // [E] gate phase: update h, write hb(t+1), write LN partials(t)
        {
            const unsigned short* gsh = (const unsigned short*)giS;
            float sacc[4], qacc[4];
#pragma unroll
            for (int r = 0; r < 4; ++r) {
                const int row = kg * 4 + r;
                float sc = 0.f, qc = 0.f;
#pragma unroll
                for (int j2 = 0; j2 < 2; ++j2) {
                    const int col = cw0 + j2 * 16 + lc;
                    const float ir  = b2f(gsh[row * 1544 + col]);
                    const float iz  = b2f(gsh[row * 1544 + 512 + col]);
                    const float inn = b2f(gsh[row * 1544 + 1024 + col]);
                    const float hr = acc[j2][r]     + bh[j2];
                    const float hz = acc[2 + j2][r] + bh[2 + j2];
                    const float hn = acc[4 + j2][r] + bh[4 + j2];
                    const float rg = 1.f / (1.f + __expf(-(ir + hr)));
                    const float zg = 1.f / (1.f + __expf(-(iz + hz)));
                    const float e2 = __expf(2.f * (inn + rg * hn));
                    const float ng = 1.f - 2.f / (e2 + 1.f);   // tanh
                    const float hv = (1.f - zg) * ng + zg * (hreg[j2][r] * mcur[r]);
                    hreg[j2][r] = hv;
                    hb[row][col] = __float2bfloat16(hv * mnx[r]);
                    sc += hv; qc += hv * hv;
                }
                sacc[r] = sc; qacc[r] = qc;
            }
#pragma unroll
            for (int m = 1; m < 16; m <<= 1)
#pragma unroll
                for (int r = 0; r < 4; ++r) {
                    sacc[r] += __shfl_xor(sacc[r], m);
                    qacc[r] += __shfl_xor(qacc[r], m);
                }
            if (lc == 0) {
#pragma unroll
                for (int r = 0; r < 4; ++r) {
                    lnS[kg * 4 + r][w] = sacc[r];
                    lnQ[kg * 4 + r][w] = qacc[r];
                }
            }
        }

        __syncthreads();   // [F] hb(t+1), lnS(t) visible; giS reads done

        // [G] issue gi(t+1)
        if (t < 127) {
            const char* gsrc = (const char*)gi + ((size_t)(t + 1) * 512 + n0 + w) * 3072;
            char* ldst = giS + (size_t)w * 3088;
#pragma unroll
            for (int i = 0; i < 3; ++i)
                load_lds16(gsrc + i * 1024 + lane * 16, ldst + i * 1024);
        }
    }

    // ---- epilogue: LN-finalize(127) + hT ----
#pragma unroll
    for (int r = 0; r < 4; ++r) {
        const int row = kg * 4 + r;
        float s = 0.f, q = 0.f;
#pragma unroll
        for (int q4 = 0; q4 < 4; ++q4) {
            f32x4 vs = *(const f32x4*)&lnS[row][q4 * 4];
            f32x4 vq = *(const f32x4*)&lnQ[row][q4 * 4];
            s += vs[0] + vs[1] + vs[2] + vs[3];
            q += vq[0] + vq[1] + vq[2] + vq[3];
        }
        const float mu   = s * (1.f / 512.f);
        const float var  = q * (1.f / 512.f) - mu * mu;
        const float rstd = rsqrtf(var + 1e-5f);
        float* orow = out + ((size_t)127 * 512 + n0 + row) * 512;
#pragma unroll
        for (int j2 = 0; j2 < 2; ++j2) {
            const int col = cw0 + j2 * 16 + lc;
            float o = (hreg[j2][r] - mu) * rstd * grg[j2] + brb[j2];
            __builtin_nontemporal_store(o, orow + col);
            hT[(size_t)(n0 + row) * 512 + col] = hreg[j2][r];
        }
    }
}

// ---------------- launch ----------------
extern "C" void kernel_launch(void* const* d_in, const int* in_sizes, int n_in,
                              void* d_out, int out_size, void* d_ws, size_t ws_size,
                              hipStream_t stream) {
    const float* obs      = (const float*)d_in[0];
    const float* hx       = (const float*)d_in[1];
    const float* on_reset = (const float*)d_in[2];
    const float* W1  = (const float*)d_in[3];
    const float* b1  = (const float*)d_in[4];
    const float* g1  = (const float*)d_in[5];
    const float* be1 = (const float*)d_in[6];
    const float* W2  = (const float*)d_in[7];
    const float* b2  = (const float*)d_in[8];
    const float* g2  = (const float*)d_in[9];
    const float* be2 = (const float*)d_in[10];
    const float* Wih = (const float*)d_in[11];
    const float* Whh = (const float*)d_in[12];
    const float* bih = (const float*)d_in[13];
    const float* bhh = (const float*)d_in[14];
    const float* gr  = (const float*)d_in[15];
    const float* br  = (const float*)d_in[16];

    // workspace layout (bytes) — proven 272,236,544 footprint
    char* ws = (char*)d_ws;
    bf16* W1b  = (bf16*)(ws + 0);                    //   131072
    bf16* W2b  = (bf16*)(ws + 131072);               //   524288
    bf16* Wihb = (bf16*)(ws + 655360);               //  1572864
    bf16* Whhb = (bf16*)(ws + 2228224);              //  1572864
    bf16* Y    = (bf16*)(ws + 3801088);              // 67108864  (post-LN acts)
    bf16* GI   = (bf16*)(ws + 3801088 + 67108864);   // 201326592 (gi)
    bf16* X1   = GI;                                 // alias: pre-LN acts (dead before GI)
    bf16* OBSB = (bf16*)((char*)GI + 67108864);      // alias: obs bf16 (dead before GI)

    // conversions
    f32_to_bf16_vec<<<(1048576 + 255) / 256, 256, 0, stream>>>(obs, OBSB, 1048576);
    f32_to_bf16_vec<<<(8192 + 255) / 256,  256, 0, stream>>>(W1,  W1b,  8192);
    f32_to_bf16_vec<<<(32768 + 255) / 256, 256, 0, stream>>>(W2,  W2b,  32768);
    f32_to_bf16_vec<<<(98304 + 255) / 256, 256, 0, stream>>>(Wih, Wihb, 98304);
    f32_to_bf16_vec<<<(98304 + 255) / 256, 256, 0, stream>>>(Whh, Whhb, 98304);

    // MLP + gi
    gemm_xwt<128, true><<<dim3(512, 4), 256, 0, stream>>>(OBSB, W1b, b1, X1, 512);
    ln_rows512<<<16384, 256, 0, stream>>>(X1, Y, g1, be1);
    gemm_xwt<512, true><<<dim3(512, 4), 256, 0, stream>>>(Y, W2b, b2, X1, 512);
    ln_rows512<<<16384, 256, 0, stream>>>(X1, Y, g2, be2);
    gemm_xwt<512, false><<<dim3(512, 12), 256, 0, stream>>>(Y, Wihb, bih, GI, 1536);

    // GRU scan (Whh pinned register-resident, fused final LN) + hT
    float* out_p = (float*)d_out;
    float* hT_p  = out_p + (size_t)65536 * 512;
    gru_scan5<<<32, 1024, 0, stream>>>(GI, on_reset, hx, Whhb, bhh, gr, br, out_p, hT_p);
}

// Round 6
// 6331.487 us; speedup vs baseline: 1.0233x; 1.0233x over previous
//
#include <hip/hip_runtime.h>
#include <hip/hip_bf16.h>

using bf16 = __hip_bfloat16;
typedef __attribute__((ext_vector_type(8))) short short8;
typedef __attribute__((ext_vector_type(4))) float f32x4;

static __device__ __forceinline__ float b2f(unsigned short s) {
    unsigned u = ((unsigned)s) << 16;
    return __builtin_bit_cast(float, u);
}
static __device__ __forceinline__ short f2b(float f) {
    __hip_bfloat16 h = __float2bfloat16(f);
    return __builtin_bit_cast(short, h);
}
static __device__ __forceinline__ void load_lds16(const void* g, void* l) {
    __builtin_amdgcn_global_load_lds(
        (const __attribute__((address_space(1))) void*)g,
        (__attribute__((address_space(3))) void*)l, 16, 0, 0);
}

// ---------------- f32 -> bf16 conversion (8 elems/thread) ----------------
__global__ void f32_to_bf16_vec(const float* __restrict__ in, bf16* __restrict__ out, int n8) {
    int i = blockIdx.x * blockDim.x + threadIdx.x;
    if (i >= n8) return;
    const f32x4* p = (const f32x4*)(in + (size_t)i * 8);
    f32x4 a = p[0], b = p[1];
    short8 o;
    o[0] = f2b(a[0]); o[1] = f2b(a[1]); o[2] = f2b(a[2]); o[3] = f2b(a[3]);
    o[4] = f2b(b[0]); o[5] = f2b(b[1]); o[6] = f2b(b[2]); o[7] = f2b(b[3]);
    *(short8*)(out + (size_t)i * 8) = o;
}

// ---------------- GEMM: C = act(X @ W^T + bias), bf16 in/out ----------------
template<int K, bool RELU>
__global__ __launch_bounds__(256) void gemm_xwt(
    const bf16* __restrict__ X, const bf16* __restrict__ W,
    const float* __restrict__ bias, bf16* __restrict__ C, int Nout)
{
    __shared__ bf16 As[128][40];
    __shared__ bf16 Bs[128][40];
    const int tid  = threadIdx.x;
    const int wave = tid >> 6, lane = tid & 63;
    const int wr = wave >> 1, wc = wave & 1;
    const long Mbase = (long)blockIdx.x * 128;
    const int  Nbase = blockIdx.y * 128;
    const int kg = (lane >> 4) * 8;

    f32x4 acc[4][4];
#pragma unroll
    for (int i = 0; i < 4; ++i)
#pragma unroll
        for (int j = 0; j < 4; ++j) acc[i][j] = (f32x4){0.f, 0.f, 0.f, 0.f};

    for (int kb = 0; kb < K / 32; ++kb) {
        __syncthreads();
#pragma unroll
        for (int q = 0; q < 2; ++q) {
            int idx = q * 256 + tid;
            int row = idx >> 2, kp = (idx & 3) * 8;
            *(short8*)&As[row][kp] = *(const short8*)&X[(Mbase + row) * K + kb * 32 + kp];
            *(short8*)&Bs[row][kp] = *(const short8*)&W[(long)(Nbase + row) * K + kb * 32 + kp];
        }
        __syncthreads();
        short8 a[4], b[4];
#pragma unroll
        for (int mt = 0; mt < 4; ++mt)
            a[mt] = *(const short8*)&As[wr * 64 + mt * 16 + (lane & 15)][kg];
#pragma unroll
        for (int nt = 0; nt < 4; ++nt)
            b[nt] = *(const short8*)&Bs[wc * 64 + nt * 16 + (lane & 15)][kg];
#pragma unroll
        for (int mt = 0; mt < 4; ++mt)
#pragma unroll
            for (int nt = 0; nt < 4; ++nt)
                acc[mt][nt] = __builtin_amdgcn_mfma_f32_16x16x32_bf16(a[mt], b[nt], acc[mt][nt], 0, 0, 0);
    }

#pragma unroll
    for (int mt = 0; mt < 4; ++mt) {
        int row0 = wr * 64 + mt * 16 + (lane >> 4) * 4;
#pragma unroll
        for (int nt = 0; nt < 4; ++nt) {
            int col = Nbase + wc * 64 + nt * 16 + (lane & 15);
            float bv = bias[col];
#pragma unroll
            for (int r = 0; r < 4; ++r) {
                float v = acc[mt][nt][r] + bv;
                if (RELU) v = fmaxf(v, 0.f);
                C[(Mbase + row0 + r) * (long)Nout + col] = __float2bfloat16(v);
            }
        }
    }
}

// ---------------- LayerNorm rows of 512, bf16 -> bf16 ----------------
__global__ __launch_bounds__(256) void ln_rows512(
    const bf16* __restrict__ in, bf16* __restrict__ out,
    const float* __restrict__ g, const float* __restrict__ be)
{
    const int lane = threadIdx.x & 63;
    const long row = (long)blockIdx.x * 4 + (threadIdx.x >> 6);
    const bf16* rp = in + row * 512;
    short8 v = *(const short8*)&rp[lane * 8];
    float x[8]; float s = 0.f, sq = 0.f;
#pragma unroll
    for (int j = 0; j < 8; ++j) { x[j] = b2f((unsigned short)v[j]); s += x[j]; sq += x[j] * x[j]; }
#pragma unroll
    for (int m = 1; m < 64; m <<= 1) { s += __shfl_xor(s, m); sq += __shfl_xor(sq, m); }
    float mu   = s * (1.f / 512.f);
    float var  = sq * (1.f / 512.f) - mu * mu;
    float rstd = rsqrtf(var + 1e-5f);
    short8 o;
#pragma unroll
    for (int j = 0; j < 8; ++j) {
        int c = lane * 8 + j;
        o[j] = f2b((x[j] - mu) * rstd * g[c] + be[c]);
    }
    *(short8*)(out + row * 512 + lane * 8) = o;
}

// ---------------- GRU scan v6: Whh streamed L2 -> per-wave LDS dbuf ----------------
// 32 blocks x 16 batch rows, 16 waves. Wave w owns h-cols [32w,32w+32) for all
// 3 gates (96 gh cols). Per step it streams its 96KB Whh slice in 24 subtiles
// (16 rows x 128 K = 4KB) via global_load_lds into a private 2x4KB LDS dbuf,
// pipelined with per-wave s_waitcnt vmcnt(4) (no barriers in the stream loop).
// Source-XOR swizzle + XOR'd ds_read_b128 keeps B-frag reads bank-uniform.
// h master f32 in regs; h exchanged via LDS hb (pre-masked bf16); fused LN.
__global__ __launch_bounds__(1024) void gru_scan6(
    const bf16* __restrict__ gi, const float* __restrict__ on_reset,
    const float* __restrict__ hx, const bf16* __restrict__ Whh,
    const float* __restrict__ bhh, const float* __restrict__ gr,
    const float* __restrict__ br, float* __restrict__ out, float* __restrict__ hT)
{
    __shared__ char  wlds[16 * 8192];  // 128 KB: per-wave 2 x 4KB W dbuf
    __shared__ bf16  hb[16][520];      // bf16 h (pre-masked), row stride 1040B
    __shared__ float lnS[16][16];
    __shared__ float lnQ[16][16];

    const int tid = threadIdx.x;
    const int w   = tid >> 6, lane = tid & 63;
    const int lc  = lane & 15, kg = lane >> 4;
    const int n0  = blockIdx.x * 16;
    const int cw0 = w * 32;
    char* wbuf = wlds + w * 8192;

    // staging lane offsets (src-XOR swizzle, parity of 4-row issue index)
    const int offE = kg * 1024 + ((lc << 4) ^ ((kg & 7) << 4));
    const int offO = kg * 1024 + ((lc << 4) ^ (((kg + 4) & 7) << 4));
    // ds_read lane offsets per kcl (XOR matches source swizzle)
    int bofs[4];
#pragma unroll
    for (int kcl = 0; kcl < 4; ++kcl)
        bofs[kcl] = lc * 256 + ((kcl * 64 + kg * 16) ^ ((lc & 7) << 4));

    // uniform row-base pointers for the 6 col-tiles (gate, half)
    const char* wrowbase[6];
#pragma unroll
    for (int ct = 0; ct < 6; ++ct) {
        const int gRow = (ct >> 1) * 512 + cw0 + (ct & 1) * 16;
        wrowbase[ct] = (const char*)Whh + (size_t)gRow * 1024;
    }

#define STAGE_SUB(ct, kq, buf) do {                                        \
        const char* sb_ = wrowbase[ct] + (kq) * 256;                       \
        char* lb_ = wbuf + (buf) * 4096;                                   \
        load_lds16(sb_ + offE,          lb_);                              \
        load_lds16(sb_ + 4096  + offO,  lb_ + 1024);                       \
        load_lds16(sb_ + 8192  + offE,  lb_ + 2048);                       \
        load_lds16(sb_ + 12288 + offO,  lb_ + 3072);                       \
    } while (0)

    // ---- hoisted per-lane constants ----
    float bh[6], grg[2], brb[2];
#pragma unroll
    for (int j2 = 0; j2 < 2; ++j2) {
        const int col = cw0 + j2 * 16 + lc;
        bh[j2]     = bhh[col];
        bh[2 + j2] = bhh[512 + col];
        bh[4 + j2] = bhh[1024 + col];
        grg[j2] = gr[col];
        brb[j2] = br[col];
    }

    // ---- h master init + hb(0) ----
    float hreg[2][4];
#pragma unroll
    for (int r = 0; r < 4; ++r) {
        const int row = kg * 4 + r;
        const float m0 = on_reset[n0 + row];
#pragma unroll
        for (int j2 = 0; j2 < 2; ++j2) {
            const int col = cw0 + j2 * 16 + lc;
            float v = hx[(size_t)(n0 + row) * 512 + col];
            hreg[j2][r] = v;
            hb[row][col] = __float2bfloat16(v * m0);
        }
    }
    STAGE_SUB(0, 0, 0);   // prologue: first subtile of step 0 in flight
    __syncthreads();

#pragma unroll 1
    for (int t = 0; t < 128; ++t) {
        // [A] masks for t and t+1
        float mcur[4], mnx[4];
#pragma unroll
        for (int r = 0; r < 4; ++r) {
            const int row = kg * 4 + r;
            mcur[r] = on_reset[(size_t)t * 512 + n0 + row];
            mnx[r]  = (t < 127) ? on_reset[(size_t)(t + 1) * 512 + n0 + row] : 1.f;
        }

        // [B] A-frags from hb (kept in regs for the whole step)
        short8 aF[16];
#pragma unroll
        for (int kc = 0; kc < 16; ++kc)
            aF[kc] = *(const short8*)&hb[lc][kc * 32 + kg * 8];

        f32x4 acc[6];
#pragma unroll
        for (int ct = 0; ct < 6; ++ct) acc[ct] = (f32x4){0.f, 0.f, 0.f, 0.f};

        // [S] streamed MFMA over 24 subtiles (wave-private pipeline)
#pragma unroll
        for (int s = 0; s < 24; ++s) {
            const int ct = s >> 2, kq = s & 3, buf = s & 1;
            if (s < 23) {
                const int sn = s + 1;
                STAGE_SUB(sn >> 2, sn & 3, sn & 1);
                asm volatile("s_waitcnt vmcnt(4)" ::: "memory");
            } else {
                asm volatile("s_waitcnt vmcnt(0)" ::: "memory");
            }
            __builtin_amdgcn_sched_barrier(0);
#pragma unroll
            for (int kcl = 0; kcl < 4; ++kcl) {
                short8 b = *(const short8*)(wbuf + buf * 4096 + bofs[kcl]);
                acc[ct] = __builtin_amdgcn_mfma_f32_16x16x32_bf16(aF[kq * 4 + kcl], b, acc[ct], 0, 0, 0);
            }
        }
        // pre-issue first subtile of step t+1 (buf0 free; hides DMA latency)
        if (t < 127) STAGE_SUB(0, 0, 0);

        // [C] LN-finalize(t-1) + coalesced out stores
        if (t > 0) {
#pragma unroll
            for (int r = 0; r < 4; ++r) {
                const int row = kg * 4 + r;
                float s = 0.f, q = 0.f;
#pragma unroll
                for (int q4 = 0; q4 < 4; ++q4) {
                    f32x4 vs = *(const f32x4*)&lnS[row][q4 * 4];
                    f32x4 vq = *(const f32x4*)&lnQ[row][q4 * 4];
                    s += vs[0] + vs[1] + vs[2] + vs[3];
                    q += vq[0] + vq[1] + vq[2] + vq[3];
                }
                const float mu   = s * (1.f / 512.f);
                const float var  = q * (1.f / 512.f) - mu * mu;
                const float rstd = rsqrtf(var + 1e-5f);
                float* orow = out + ((size_t)(t - 1) * 512 + n0 + row) * 512;
#pragma unroll
                for (int j2 = 0; j2 < 2; ++j2) {
                    const int col = cw0 + j2 * 16 + lc;
                    float o = (hreg[j2][r] - mu) * rstd * grg[j2] + brb[j2];
                    __builtin_nontemporal_store(o, orow + col);
                }
            }
        }

        __syncthreads();   // [D] hb reads done; lnS reads done

        // [E] gate phase: gi direct (nontemporal), update h, write hb(t+1), LN partials
        {
            const size_t gibase = ((size_t)t * 512 + n0) * 1536;
            const unsigned short* gib = (const unsigned short*)gi;
            float sacc[4], qacc[4];
#pragma unroll
            for (int r = 0; r < 4; ++r) {
                const int row = kg * 4 + r;
                const unsigned short* gp = gib + gibase + (size_t)row * 1536;
                float sc = 0.f, qc = 0.f;
#pragma unroll
                for (int j2 = 0; j2 < 2; ++j2) {
                    const int col = cw0 + j2 * 16 + lc;
                    const float ir  = b2f(__builtin_nontemporal_load(gp + col));
                    const float iz  = b2f(__builtin_nontemporal_load(gp + 512 + col));
                    const float inn = b2f(__builtin_nontemporal_load(gp + 1024 + col));
                    const float hr = acc[j2][r]     + bh[j2];
                    const float hz = acc[2 + j2][r] + bh[2 + j2];
                    const float hn = acc[4 + j2][r] + bh[4 + j2];
                    const float rg = 1.f / (1.f + __expf(-(ir + hr)));
                    const float zg = 1.f / (1.f + __expf(-(iz + hz)));
                    const float e2 = __expf(2.f * (inn + rg * hn));
                    const float ng = 1.f - 2.f / (e2 + 1.f);   // tanh
                    const float hv = (1.f - zg) * ng + zg * (hreg[j2][r] * mcur[r]);
                    hreg[j2][r] = hv;
                    hb[row][col] = __float2bfloat16(hv * mnx[r]);
                    sc += hv; qc += hv * hv;
                }
                sacc[r] = sc; qacc[r] = qc;
            }
#pragma unroll
            for (int m = 1; m < 16; m <<= 1)
#pragma unroll
                for (int r = 0; r < 4; ++r) {
                    sacc[r] += __shfl_xor(sacc[r], m);
                    qacc[r] += __shfl_xor(qacc[r], m);
                }
            if (lc == 0) {
#pragma unroll
                for (int r = 0; r < 4; ++r) {
                    lnS[kg * 4 + r][w] = sacc[r];
                    lnQ[kg * 4 + r][w] = qacc[r];
                }
            }
        }

        __syncthreads();   // [F] hb(t+1), lnS(t) visible
    }

    // ---- epilogue: LN-finalize(127) + hT ----
#pragma unroll
    for (int r = 0; r < 4; ++r) {
        const int row = kg * 4 + r;
        float s = 0.f, q = 0.f;
#pragma unroll
        for (int q4 = 0; q4 < 4; ++q4) {
            f32x4 vs = *(const f32x4*)&lnS[row][q4 * 4];
            f32x4 vq = *(const f32x4*)&lnQ[row][q4 * 4];
            s += vs[0] + vs[1] + vs[2] + vs[3];
            q += vq[0] + vq[1] + vq[2] + vq[3];
        }
        const float mu   = s * (1.f / 512.f);
        const float var  = q * (1.f / 512.f) - mu * mu;
        const float rstd = rsqrtf(var + 1e-5f);
        float* orow = out + ((size_t)127 * 512 + n0 + row) * 512;
#pragma unroll
        for (int j2 = 0; j2 < 2; ++j2) {
            const int col = cw0 + j2 * 16 + lc;
            float o = (hreg[j2][r] - mu) * rstd * grg[j2] + brb[j2];
            __builtin_nontemporal_store(o, orow + col);
            hT[(size_t)(n0 + row) * 512 + col] = hreg[j2][r];
        }
    }
#undef STAGE_SUB
}

// ---------------- launch ----------------
extern "C" void kernel_launch(void* const* d_in, const int* in_sizes, int n_in,
                              void* d_out, int out_size, void* d_ws, size_t ws_size,
                              hipStream_t stream) {
    const float* obs      = (const float*)d_in[0];
    const float* hx       = (const float*)d_in[1];
    const float* on_reset = (const float*)d_in[2];
    const float* W1  = (const float*)d_in[3];
    const float* b1  = (const float*)d_in[4];
    const float* g1  = (const float*)d_in[5];
    const float* be1 = (const float*)d_in[6];
    const float* W2  = (const float*)d_in[7];
    const float* b2  = (const float*)d_in[8];
    const float* g2  = (const float*)d_in[9];
    const float* be2 = (const float*)d_in[10];
    const float* Wih = (const float*)d_in[11];
    const float* Whh = (const float*)d_in[12];
    const float* bih = (const float*)d_in[13];
    const float* bhh = (const float*)d_in[14];
    const float* gr  = (const float*)d_in[15];
    const float* br  = (const float*)d_in[16];

    // workspace layout (bytes) — proven 272,236,544 footprint
    char* ws = (char*)d_ws;
    bf16* W1b  = (bf16*)(ws + 0);                    //   131072
    bf16* W2b  = (bf16*)(ws + 131072);               //   524288
    bf16* Wihb = (bf16*)(ws + 655360);               //  1572864
    bf16* Whhb = (bf16*)(ws + 2228224);              //  1572864
    bf16* Y    = (bf16*)(ws + 3801088);              // 67108864  (post-LN acts)
    bf16* GI   = (bf16*)(ws + 3801088 + 67108864);   // 201326592 (gi)
    bf16* X1   = GI;                                 // alias: pre-LN acts (dead before GI)
    bf16* OBSB = (bf16*)((char*)GI + 67108864);      // alias: obs bf16 (dead before GI)

    // conversions
    f32_to_bf16_vec<<<(1048576 + 255) / 256, 256, 0, stream>>>(obs, OBSB, 1048576);
    f32_to_bf16_vec<<<(8192 + 255) / 256,  256, 0, stream>>>(W1,  W1b,  8192);
    f32_to_bf16_vec<<<(32768 + 255) / 256, 256, 0, stream>>>(W2,  W2b,  32768);
    f32_to_bf16_vec<<<(98304 + 255) / 256, 256, 0, stream>>>(Wih, Wihb, 98304);
    f32_to_bf16_vec<<<(98304 + 255) / 256, 256, 0, stream>>>(Whh, Whhb, 98304);

    // MLP + gi
    gemm_xwt<128, true><<<dim3(512, 4), 256, 0, stream>>>(OBSB, W1b, b1, X1, 512);
    ln_rows512<<<16384, 256, 0, stream>>>(X1, Y, g1, be1);
    gemm_xwt<512, true><<<dim3(512, 4), 256, 0, stream>>>(Y, W2b, b2, X1, 512);
    ln_rows512<<<16384, 256, 0, stream>>>(X1, Y, g2, be2);
    gemm_xwt<512, false><<<dim3(512, 12), 256, 0, stream>>>(Y, Wihb, bih, GI, 1536);

    // GRU scan (L2->LDS streamed Whh, fused final LN) + hT
    float* out_p = (float*)d_out;
    float* hT_p  = out_p + (size_t)65536 * 512;
    gru_scan6<<<32, 1024, 0, stream>>>(GI, on_reset, hx, Whhb, bhh, gr, br, out_p, hT_p);
}